// Round 1
// baseline (9279.887 us; speedup 1.0000x reference)
//
#include <hip/hip_runtime.h>
#include <math.h>

#define BB 4
#define HH 480
#define WW 640
#define HW (HH * WW)
#define PP (BB * HW)   // 1,228,800 pixels; PP % 256 == 0 (4800 blocks)

// Bilinear corner load with zero padding (matches reference: clip index, mask value)
__device__ __forceinline__ float ldz(const float* __restrict__ img, int y, int x) {
    bool v = ((unsigned)y < (unsigned)HH) & ((unsigned)x < (unsigned)WW);
    int off = v ? (y * WW + x) : 0;
    float val = img[off];
    return v ? val : 0.0f;
}

// ---------------------------------------------------------------------------
// Kernel 1: per-pixel precompute.
// conv(guidance; 8ch, 3x3) -> 24ch = [off_y(8), off_x(8), aff_raw(8)]
// aff = tanh(aff_raw)/(scale+1e-8) * bilinear(confidence, p+off)
// abs-sum norm (clamped at 1), aff_ref = 1-sum, softmax over 9.
// Writes: affC[P], affNC[8][P], Ys[8][P], Xs[8][P]  (tap-major SoA, coalesced)
// ---------------------------------------------------------------------------
__global__ __launch_bounds__(256) void precompute_kernel(
    const float* __restrict__ guidance,
    const float* __restrict__ confidence,
    const float* __restrict__ w_oa,
    const float* __restrict__ b_oa,
    const float* __restrict__ aff_scale,
    float* __restrict__ affC,
    float* __restrict__ affNC,
    float* __restrict__ Ys,
    float* __restrict__ Xs)
{
    __shared__ __align__(16) float w_lds[1728];  // transposed: [k=ci*9+kidx][c=0..23]
    __shared__ float b_lds[24];
    const int tid = threadIdx.x;
    for (int i = tid; i < 1728; i += 256) {
        int k = i / 24, c = i - k * 24;
        w_lds[i] = w_oa[c * 72 + k];   // src layout [c][ci][ky][kx]
    }
    if (tid < 24) b_lds[tid] = b_oa[tid];
    __syncthreads();

    const int p = blockIdx.x * 256 + tid;
    const int b = p / HW;
    const int rem = p - b * HW;
    const int y = rem / WW;
    const int x = rem - y * WW;

    float acc[24];
    #pragma unroll
    for (int c = 0; c < 24; ++c) acc[c] = b_lds[c];

    const float* gb = guidance + (size_t)b * 8 * HW;
    #pragma unroll
    for (int kidx = 0; kidx < 9; ++kidx) {
        const int dy = kidx / 3 - 1, dx = kidx % 3 - 1;
        const int yy = y + dy, xx = x + dx;
        const bool valid = ((unsigned)yy < (unsigned)HH) & ((unsigned)xx < (unsigned)WW);
        const int base = valid ? (yy * WW + xx) : 0;
        #pragma unroll
        for (int ci = 0; ci < 8; ++ci) {
            float g = gb[ci * HW + base];
            g = valid ? g : 0.0f;
            const float4* wrow = reinterpret_cast<const float4*>(&w_lds[(ci * 9 + kidx) * 24]);
            #pragma unroll
            for (int q = 0; q < 6; ++q) {
                float4 w4 = wrow[q];
                acc[q * 4 + 0] = fmaf(g, w4.x, acc[q * 4 + 0]);
                acc[q * 4 + 1] = fmaf(g, w4.y, acc[q * 4 + 1]);
                acc[q * 4 + 2] = fmaf(g, w4.z, acc[q * 4 + 2]);
                acc[q * 4 + 3] = fmaf(g, w4.w, acc[q * 4 + 3]);
            }
        }
    }

    // --- affinity head ---
    const float inv_scale = 1.0f / (aff_scale[0] + 1e-8f);
    const float* cb = confidence + (size_t)b * HW;
    const float fy = (float)y, fx = (float)x;

    float affv[8];
    #pragma unroll
    for (int j = 0; j < 8; ++j) {
        const float oy = acc[j], ox = acc[8 + j];
        const float a = tanhf(acc[16 + j]) * inv_scale;
        const float ysj = fy + oy, xsj = fx + ox;
        const float y0f = floorf(ysj), x0f = floorf(xsj);
        const float wy = ysj - y0f, wx = xsj - x0f;
        const int y0 = (int)y0f, x0 = (int)x0f;
        const float v00 = ldz(cb, y0, x0),     v01 = ldz(cb, y0, x0 + 1);
        const float v10 = ldz(cb, y0 + 1, x0), v11 = ldz(cb, y0 + 1, x0 + 1);
        const float conf = v00 * (1.0f - wy) * (1.0f - wx) + v01 * (1.0f - wy) * wx
                         + v10 * wy * (1.0f - wx)          + v11 * wy * wx;
        affv[j] = a * conf;
    }

    float s = 1e-4f;
    #pragma unroll
    for (int j = 0; j < 8; ++j) s += fabsf(affv[j]);
    s = fmaxf(s, 1.0f);
    const float inv_s = 1.0f / s;
    float sum = 0.0f;
    #pragma unroll
    for (int j = 0; j < 8; ++j) { affv[j] *= inv_s; sum += affv[j]; }
    const float aref = 1.0f - sum;

    // stable softmax over 9 = [affv[0..3], aref, affv[4..7]]
    float m = aref;
    #pragma unroll
    for (int j = 0; j < 8; ++j) m = fmaxf(m, affv[j]);
    float e[8];
    float denom = 0.0f;
    #pragma unroll
    for (int j = 0; j < 8; ++j) { e[j] = expf(affv[j] - m); denom += e[j]; }
    const float ec = expf(aref - m);
    denom += ec;
    const float invden = 1.0f / denom;

    affC[p] = ec * invden;
    #pragma unroll
    for (int j = 0; j < 8; ++j) {
        const int t = (j < 4) ? j : j + 1;          // 9-tap index (skip center 4)
        const float khv = (float)(t / 3 - 1);
        const float kwv = (float)(t % 3 - 1);
        affNC[j * PP + p] = e[j] * invden;
        Ys[j * PP + p] = (fy + khv) + acc[j];
        Xs[j * PP + p] = (fx + kwv) + acc[8 + j];
    }
}

// ---------------------------------------------------------------------------
// Kernel 2: one propagation step. 18 launches, ping-pong buffers.
// ---------------------------------------------------------------------------
__global__ __launch_bounds__(256) void prop_kernel(
    const float* __restrict__ src,
    float* __restrict__ dst,
    const float* __restrict__ affC,
    const float* __restrict__ affNC,
    const float* __restrict__ Ys,
    const float* __restrict__ Xs)
{
    const int p = blockIdx.x * 256 + threadIdx.x;
    const int b = p / HW;
    const float* fb = src + (size_t)b * HW;

    float acc = affC[p] * src[p];   // center tap: exact sample at p
    #pragma unroll
    for (int j = 0; j < 8; ++j) {
        const float a  = affNC[j * PP + p];
        const float ys = Ys[j * PP + p];
        const float xs = Xs[j * PP + p];
        const float y0f = floorf(ys), x0f = floorf(xs);
        const float wy = ys - y0f, wx = xs - x0f;
        const int y0 = (int)y0f, x0 = (int)x0f;
        const float v00 = ldz(fb, y0, x0),     v01 = ldz(fb, y0, x0 + 1);
        const float v10 = ldz(fb, y0 + 1, x0), v11 = ldz(fb, y0 + 1, x0 + 1);
        const float top = v00 + wx * (v01 - v00);
        const float bot = v10 + wx * (v11 - v10);
        acc = fmaf(a, top + wy * (bot - top), acc);
    }
    dst[p] = acc;
}

extern "C" void kernel_launch(void* const* d_in, const int* in_sizes, int n_in,
                              void* d_out, int out_size, void* d_ws, size_t ws_size,
                              hipStream_t stream) {
    const float* feat_init  = (const float*)d_in[0];
    const float* guidance   = (const float*)d_in[1];
    const float* confidence = (const float*)d_in[2];
    const float* w_oa       = (const float*)d_in[3];
    const float* b_oa       = (const float*)d_in[4];
    const float* aff_scale  = (const float*)d_in[5];
    float* out = (float*)d_out;
    float* ws  = (float*)d_ws;

    // ws layout (floats): affC[P] | affNC[8P] | Ys[8P] | Xs[8P] | bufA[P]
    const size_t need = (size_t)26 * PP * sizeof(float);
    if (ws_size < need) return;  // fail visibly (poison output) rather than corrupt

    float* affC  = ws;
    float* affNC = ws + (size_t)PP;
    float* Ys    = ws + (size_t)9 * PP;
    float* Xs    = ws + (size_t)17 * PP;
    float* bufA  = ws + (size_t)25 * PP;

    const int grid = PP / 256;
    precompute_kernel<<<grid, 256, 0, stream>>>(guidance, confidence, w_oa, b_oa,
                                                aff_scale, affC, affNC, Ys, Xs);

    // ping-pong: even iters -> bufA, odd iters -> d_out (iter 17 is odd -> d_out)
    const float* src = feat_init;
    for (int i = 0; i < 18; ++i) {
        float* dst = (i & 1) ? out : bufA;
        prop_kernel<<<grid, 256, 0, stream>>>(src, dst, affC, affNC, Ys, Xs);
        src = dst;
    }
}

// Round 2
// 973.982 us; speedup vs baseline: 9.5278x; 9.5278x over previous
//
#include <hip/hip_runtime.h>
#include <math.h>

#define BB 4
#define HH 480
#define WW 640
#define HW (HH * WW)
#define PP (BB * HW)   // 1,228,800 pixels; PP % 256 == 0 (4800 blocks)

// Bilinear corner load with zero padding (matches reference: clip index, mask value)
__device__ __forceinline__ float ldz(const float* __restrict__ img, int y, int x) {
    bool v = ((unsigned)y < (unsigned)HH) & ((unsigned)x < (unsigned)WW);
    int off = v ? (y * WW + x) : 0;
    float val = img[off];
    return v ? val : 0.0f;
}

// ---------------------------------------------------------------------------
// Kernel 0: transpose weights [c=24][ci=8][k=9] -> wT[k=9][ci=8][c=24]
// so the per-(k,ci) 24 weights are contiguous -> wide scalar loads (s_load_dwordxN)
// ---------------------------------------------------------------------------
__global__ void transpose_w_kernel(const float* __restrict__ w_oa, float* __restrict__ wT) {
    for (int i = threadIdx.x; i < 1728; i += 256) {
        const int k = i / 192;            // 0..8
        const int r = i - k * 192;
        const int ci = r / 24;            // 0..7
        const int c = r - ci * 24;        // 0..23
        wT[i] = w_oa[c * 72 + ci * 9 + k];
    }
}

// ---------------------------------------------------------------------------
// Kernel 1: per-pixel precompute.
// conv(guidance; 8ch, 3x3) -> 24ch = [off_y(8), off_x(8), aff_raw(8)]
// aff = tanh(aff_raw)/(scale+1e-8) * bilinear(confidence, p+off)
// abs-sum norm (clamped at 1), aff_ref = 1-sum, softmax over 9.
// Writes: affNC[8][P], YX[8][P] (float2). Center aff is derived in prop
// (softmax sums to 1 -> affC = 1 - sum(affNC)).
// Weights read via wave-uniform scalar loads (SGPR operand of v_fmac) — no LDS,
// no VGPR pressure from weights.  kidx loop NOT unrolled to keep live set small.
// ---------------------------------------------------------------------------
__global__ __launch_bounds__(256) void precompute_kernel(
    const float* __restrict__ guidance,
    const float* __restrict__ confidence,
    const float* __restrict__ wT,
    const float* __restrict__ b_oa,
    const float* __restrict__ aff_scale,
    float* __restrict__ affNC,
    float2* __restrict__ YX)
{
    const int p = blockIdx.x * 256 + threadIdx.x;
    const int b = p / HW;
    const int rem = p - b * HW;
    const int y = rem / WW;
    const int x = rem - y * WW;

    float acc[24];
    #pragma unroll
    for (int c = 0; c < 24; ++c) acc[c] = b_oa[c];   // uniform -> s_load

    const float* gb = guidance + (size_t)b * 8 * HW;

    #pragma unroll 1
    for (int kidx = 0; kidx < 9; ++kidx) {
        const int yy = y + kidx / 3 - 1;
        const int xx = x + kidx % 3 - 1;
        const bool valid = ((unsigned)yy < (unsigned)HH) & ((unsigned)xx < (unsigned)WW);
        const int base = valid ? (yy * WW + xx) : 0;
        float g[8];
        #pragma unroll
        for (int ci = 0; ci < 8; ++ci) {
            float v = gb[ci * HW + base];
            g[ci] = valid ? v : 0.0f;
        }
        const float* wk = wT + kidx * 192;   // uniform address -> scalar loads
        #pragma unroll
        for (int ci = 0; ci < 8; ++ci) {
            const float gv = g[ci];
            #pragma unroll
            for (int c = 0; c < 24; ++c)
                acc[c] = fmaf(gv, wk[ci * 24 + c], acc[c]);
        }
    }

    // --- affinity head ---
    const float inv_scale = 1.0f / (aff_scale[0] + 1e-8f);
    const float* cb = confidence + (size_t)b * HW;
    const float fy = (float)y, fx = (float)x;

    float affv[8];
    #pragma unroll
    for (int j = 0; j < 8; ++j) {
        const float oy = acc[j], ox = acc[8 + j];
        const float a = tanhf(acc[16 + j]) * inv_scale;
        const float ysj = fy + oy, xsj = fx + ox;   // conf sampled at p+off (no kernel tap)
        const float y0f = floorf(ysj), x0f = floorf(xsj);
        const float wy = ysj - y0f, wx = xsj - x0f;
        const int y0 = (int)y0f, x0 = (int)x0f;
        const float v00 = ldz(cb, y0, x0),     v01 = ldz(cb, y0, x0 + 1);
        const float v10 = ldz(cb, y0 + 1, x0), v11 = ldz(cb, y0 + 1, x0 + 1);
        const float conf = v00 * (1.0f - wy) * (1.0f - wx) + v01 * (1.0f - wy) * wx
                         + v10 * wy * (1.0f - wx)          + v11 * wy * wx;
        affv[j] = a * conf;
    }

    float s = 1e-4f;
    #pragma unroll
    for (int j = 0; j < 8; ++j) s += fabsf(affv[j]);
    s = fmaxf(s, 1.0f);
    const float inv_s = 1.0f / s;
    float sum = 0.0f;
    #pragma unroll
    for (int j = 0; j < 8; ++j) { affv[j] *= inv_s; sum += affv[j]; }
    const float aref = 1.0f - sum;

    // stable softmax over 9 = [affv[0..3], aref, affv[4..7]]
    float m = aref;
    #pragma unroll
    for (int j = 0; j < 8; ++j) m = fmaxf(m, affv[j]);
    float e[8];
    float denom = 0.0f;
    #pragma unroll
    for (int j = 0; j < 8; ++j) { e[j] = expf(affv[j] - m); denom += e[j]; }
    denom += expf(aref - m);
    const float invden = 1.0f / denom;

    #pragma unroll
    for (int j = 0; j < 8; ++j) {
        const int t = (j < 4) ? j : j + 1;          // 9-tap index (skip center 4)
        const float khv = (float)(t / 3 - 1);
        const float kwv = (float)(t % 3 - 1);
        affNC[j * PP + p] = e[j] * invden;
        YX[(size_t)j * PP + p] = make_float2((fy + khv) + acc[j], (fx + kwv) + acc[8 + j]);
    }
}

// ---------------------------------------------------------------------------
// Kernel 2: one propagation step. 18 launches, ping-pong buffers.
// Center weight = 1 - sum(aff) (softmax over 9 sums to 1) — saves one stream.
// ---------------------------------------------------------------------------
__global__ __launch_bounds__(256) void prop_kernel(
    const float* __restrict__ src,
    float* __restrict__ dst,
    const float* __restrict__ aff,
    const float2* __restrict__ YX)
{
    const int p = blockIdx.x * 256 + threadIdx.x;
    const int b = p / HW;
    const float* fb = src + (size_t)b * HW;

    float a[8];
    float2 yx[8];
    #pragma unroll
    for (int j = 0; j < 8; ++j) {
        a[j]  = aff[j * PP + p];
        yx[j] = YX[(size_t)j * PP + p];
    }
    float s = 0.0f;
    #pragma unroll
    for (int j = 0; j < 8; ++j) s += a[j];
    float acc = (1.0f - s) * src[p];   // center tap: exact sample at p

    #pragma unroll
    for (int j = 0; j < 8; ++j) {
        const float ys = yx[j].x, xs = yx[j].y;
        const float y0f = floorf(ys), x0f = floorf(xs);
        const float wy = ys - y0f, wx = xs - x0f;
        const int y0 = (int)y0f, x0 = (int)x0f;
        const float v00 = ldz(fb, y0, x0),     v01 = ldz(fb, y0, x0 + 1);
        const float v10 = ldz(fb, y0 + 1, x0), v11 = ldz(fb, y0 + 1, x0 + 1);
        const float top = v00 + wx * (v01 - v00);
        const float bot = v10 + wx * (v11 - v10);
        acc = fmaf(a[j], top + wy * (bot - top), acc);
    }
    dst[p] = acc;
}

extern "C" void kernel_launch(void* const* d_in, const int* in_sizes, int n_in,
                              void* d_out, int out_size, void* d_ws, size_t ws_size,
                              hipStream_t stream) {
    const float* feat_init  = (const float*)d_in[0];
    const float* guidance   = (const float*)d_in[1];
    const float* confidence = (const float*)d_in[2];
    const float* w_oa       = (const float*)d_in[3];
    const float* b_oa       = (const float*)d_in[4];
    const float* aff_scale  = (const float*)d_in[5];
    float* out = (float*)d_out;
    float* ws  = (float*)d_ws;

    // ws layout (floats): affNC[8P] | YX[16P] | bufA[P] | wT[1728]
    const size_t need = ((size_t)25 * PP + 1728) * sizeof(float);
    if (ws_size < need) return;  // fail visibly rather than corrupt

    float*  affNC = ws;
    float2* YX    = reinterpret_cast<float2*>(ws + (size_t)8 * PP);
    float*  bufA  = ws + (size_t)24 * PP;
    float*  wT    = ws + (size_t)25 * PP;

    const int grid = PP / 256;
    transpose_w_kernel<<<1, 256, 0, stream>>>(w_oa, wT);
    precompute_kernel<<<grid, 256, 0, stream>>>(guidance, confidence, wT, b_oa,
                                                aff_scale, affNC, YX);

    // ping-pong: even iters -> bufA, odd iters -> d_out (iter 17 is odd -> d_out)
    const float* src = feat_init;
    for (int i = 0; i < 18; ++i) {
        float* dst = (i & 1) ? out : bufA;
        prop_kernel<<<grid, 256, 0, stream>>>(src, dst, affNC, YX);
        src = dst;
    }
}

// Round 3
// 598.181 us; speedup vs baseline: 15.5135x; 1.6282x over previous
//
#include <hip/hip_runtime.h>
#include <hip/hip_fp16.h>
#include <math.h>

#define BB 4
#define HH 480
#define WW 640
#define HW (HH * WW)
#define PP (BB * HW)   // 1,228,800 pixels; PP % 256 == 0 (4800 blocks)

// Bilinear corner load with zero padding (precompute only)
__device__ __forceinline__ float ldz(const float* __restrict__ img, int y, int x) {
    bool v = ((unsigned)y < (unsigned)HH) & ((unsigned)x < (unsigned)WW);
    int off = v ? (y * WW + x) : 0;
    float val = img[off];
    return v ? val : 0.0f;
}

// Axis mapping for zero-padded bilinear on a clamped 2x2 square:
// contribution along this axis == s * [(1-t)*I[c0] + t*I[c0+1]], c0 in [0, H-2].
__device__ __forceinline__ void axis_map(int y0, float wy, int H,
                                         int& c0, float& t, float& s) {
    if (y0 >= 0 && y0 <= H - 2)      { c0 = y0;    t = wy;   s = 1.0f; }
    else if (y0 == -1)               { c0 = 0;     t = 0.0f; s = wy; }
    else if (y0 == H - 1)            { c0 = H - 2; t = 1.0f; s = 1.0f - wy; }
    else                             { c0 = 0;     t = 0.0f; s = 0.0f; }
}

// ---------------------------------------------------------------------------
// Kernel 0: transpose weights [c=24][ci=8][k=9] -> wT[k=9][ci=8][c=24]
// (wT lives in bufA's storage — dead until prop iter 0 overwrites it)
// ---------------------------------------------------------------------------
__global__ void transpose_w_kernel(const float* __restrict__ w_oa, float* __restrict__ wT) {
    for (int i = threadIdx.x; i < 1728; i += 256) {
        const int k = i / 192;
        const int r = i - k * 192;
        const int ci = r / 24;
        const int c = r - ci * 24;
        wT[i] = w_oa[c * 72 + ci * 9 + k];
    }
}

// ---------------------------------------------------------------------------
// Kernel 1: per-pixel precompute.
// conv(guidance; 8ch, 3x3) -> [off_y(8), off_x(8), aff_raw(8)]
// TGASS affinity + conf bilinear + abs-sum norm + softmax(9).
// Per tap j, prop sampling is baked into:
//   AFF[j][p] = softmax_aff_j * sy * sx          (f32)
//   BT[j][p]  = { base = y0c*W + x0c,  pack_f16(ty, tx) }   (uint2)
// plus affC[p] (center softmax weight). Prop then needs NO bounds checks.
// ---------------------------------------------------------------------------
__global__ __launch_bounds__(256) void precompute_kernel(
    const float* __restrict__ guidance,
    const float* __restrict__ confidence,
    const float* __restrict__ wT,
    const float* __restrict__ b_oa,
    const float* __restrict__ aff_scale,
    float* __restrict__ AFF,
    uint2* __restrict__ BT,
    float* __restrict__ affC)
{
    const int p = blockIdx.x * 256 + threadIdx.x;
    const int b = p / HW;
    const int rem = p - b * HW;
    const int y = rem / WW;
    const int x = rem - y * WW;

    float acc[24];
    #pragma unroll
    for (int c = 0; c < 24; ++c) acc[c] = b_oa[c];   // uniform -> s_load

    const float* gb = guidance + (size_t)b * 8 * HW;

    #pragma unroll 1
    for (int kidx = 0; kidx < 9; ++kidx) {
        const int yy = y + kidx / 3 - 1;
        const int xx = x + kidx % 3 - 1;
        const bool valid = ((unsigned)yy < (unsigned)HH) & ((unsigned)xx < (unsigned)WW);
        const int base = valid ? (yy * WW + xx) : 0;
        float g[8];
        #pragma unroll
        for (int ci = 0; ci < 8; ++ci) {
            float v = gb[ci * HW + base];
            g[ci] = valid ? v : 0.0f;
        }
        const float* wk = wT + kidx * 192;   // uniform address -> scalar loads
        #pragma unroll
        for (int ci = 0; ci < 8; ++ci) {
            const float gv = g[ci];
            #pragma unroll
            for (int c = 0; c < 24; ++c)
                acc[c] = fmaf(gv, wk[ci * 24 + c], acc[c]);
        }
    }

    // --- affinity head ---
    const float inv_scale = 1.0f / (aff_scale[0] + 1e-8f);
    const float* cb = confidence + (size_t)b * HW;
    const float fy = (float)y, fx = (float)x;

    float affv[8];
    #pragma unroll
    for (int j = 0; j < 8; ++j) {
        const float oy = acc[j], ox = acc[8 + j];
        const float a = tanhf(acc[16 + j]) * inv_scale;
        const float ysj = fy + oy, xsj = fx + ox;   // conf sampled at p+off (no tap)
        const float y0f = floorf(ysj), x0f = floorf(xsj);
        const float wy = ysj - y0f, wx = xsj - x0f;
        const int y0 = (int)y0f, x0 = (int)x0f;
        const float v00 = ldz(cb, y0, x0),     v01 = ldz(cb, y0, x0 + 1);
        const float v10 = ldz(cb, y0 + 1, x0), v11 = ldz(cb, y0 + 1, x0 + 1);
        const float conf = v00 * (1.0f - wy) * (1.0f - wx) + v01 * (1.0f - wy) * wx
                         + v10 * wy * (1.0f - wx)          + v11 * wy * wx;
        affv[j] = a * conf;
    }

    float s = 1e-4f;
    #pragma unroll
    for (int j = 0; j < 8; ++j) s += fabsf(affv[j]);
    s = fmaxf(s, 1.0f);
    const float inv_s = 1.0f / s;
    float sum = 0.0f;
    #pragma unroll
    for (int j = 0; j < 8; ++j) { affv[j] *= inv_s; sum += affv[j]; }
    const float aref = 1.0f - sum;

    float m = aref;
    #pragma unroll
    for (int j = 0; j < 8; ++j) m = fmaxf(m, affv[j]);
    float e[8];
    float denom = 0.0f;
    #pragma unroll
    for (int j = 0; j < 8; ++j) { e[j] = expf(affv[j] - m); denom += e[j]; }
    denom += expf(aref - m);
    const float invden = 1.0f / denom;

    affC[p] = expf(aref - m) * invden;

    #pragma unroll
    for (int j = 0; j < 8; ++j) {
        const int t9 = (j < 4) ? j : j + 1;          // 9-tap index (skip center 4)
        const float khv = (float)(t9 / 3 - 1);
        const float kwv = (float)(t9 % 3 - 1);
        const float ys = (fy + khv) + acc[j];
        const float xs = (fx + kwv) + acc[8 + j];
        const float y0f = floorf(ys), x0f = floorf(xs);
        const float wy = ys - y0f, wx = xs - x0f;
        int y0c, x0c; float ty, tx, sy, sx;
        axis_map((int)y0f, wy, HH, y0c, ty, sy);
        axis_map((int)x0f, wx, WW, x0c, tx, sx);

        AFF[j * PP + p] = (e[j] * invden) * sy * sx;
        __half2 h2 = __floats2half2_rn(ty, tx);      // low = ty, high = tx
        BT[(size_t)j * PP + p] = make_uint2((unsigned)(y0c * WW + x0c),
                                            __builtin_bit_cast(unsigned, h2));
    }
}

// ---------------------------------------------------------------------------
// Kernel 2: one propagation step. 18 launches, ping-pong buffers.
// Per tap: 2 stream loads + 4 in-bounds gathers (imm offsets) + 2 cvt + 7 FMA.
// ---------------------------------------------------------------------------
__global__ __launch_bounds__(256) void prop_kernel(
    const float* __restrict__ src,
    float* __restrict__ dst,
    const float* __restrict__ AFF,
    const uint2* __restrict__ BT,
    const float* __restrict__ affC)
{
    const int p = blockIdx.x * 256 + threadIdx.x;
    const int b = p / HW;
    const float* fb = src + (size_t)b * HW;

    float acc = affC[p] * src[p];   // center tap: exact sample at p

    #pragma unroll
    for (int j = 0; j < 8; ++j) {
        const float a = AFF[j * PP + p];
        const uint2 bt = BT[(size_t)j * PP + p];
        const float* g = fb + bt.x;
        const float v00 = g[0], v01 = g[1];
        const float v10 = g[WW], v11 = g[WW + 1];
        const __half2 h2 = __builtin_bit_cast(__half2, bt.y);
        const float2 t = __half22float2(h2);         // t.x = ty, t.y = tx
        const float top = fmaf(t.y, v01 - v00, v00);
        const float bot = fmaf(t.y, v11 - v10, v10);
        acc = fmaf(a, fmaf(t.x, bot - top, top), acc);
    }
    dst[p] = acc;
}

extern "C" void kernel_launch(void* const* d_in, const int* in_sizes, int n_in,
                              void* d_out, int out_size, void* d_ws, size_t ws_size,
                              hipStream_t stream) {
    const float* feat_init  = (const float*)d_in[0];
    const float* guidance   = (const float*)d_in[1];
    const float* confidence = (const float*)d_in[2];
    const float* w_oa       = (const float*)d_in[3];
    const float* b_oa       = (const float*)d_in[4];
    const float* aff_scale  = (const float*)d_in[5];
    float* out = (float*)d_out;
    float* ws  = (float*)d_ws;

    // ws layout (floats): AFF[8P] | BT[16P] | affC[P] | bufA[P]
    // wT (1728 floats) aliases bufA: dead once precompute has read it,
    // before prop iter 0 writes bufA (stream-ordered).
    const size_t need = (size_t)26 * PP * sizeof(float);
    if (ws_size < need) return;  // fail visibly rather than corrupt

    float* AFF  = ws;
    uint2* BT   = reinterpret_cast<uint2*>(ws + (size_t)8 * PP);
    float* affC = ws + (size_t)24 * PP;
    float* bufA = ws + (size_t)25 * PP;
    float* wT   = bufA;

    const int grid = PP / 256;
    transpose_w_kernel<<<1, 256, 0, stream>>>(w_oa, wT);
    precompute_kernel<<<grid, 256, 0, stream>>>(guidance, confidence, wT, b_oa,
                                                aff_scale, AFF, BT, affC);

    // ping-pong: even iters -> bufA, odd iters -> d_out (iter 17 -> d_out)
    const float* src = feat_init;
    for (int i = 0; i < 18; ++i) {
        float* dst = (i & 1) ? out : bufA;
        prop_kernel<<<grid, 256, 0, stream>>>(src, dst, AFF, BT, affC);
        src = dst;
    }
}

// Round 4
// 569.621 us; speedup vs baseline: 16.2913x; 1.0501x over previous
//
#include <hip/hip_runtime.h>
#include <hip/hip_fp16.h>
#include <math.h>

#define BB 4
#define HH 480
#define WW 640
#define HW (HH * WW)
#define PP (BB * HW)   // 1,228,800 pixels; PP % 256 == 0 (4800 blocks)

// Bilinear corner load with zero padding (precompute only)
__device__ __forceinline__ float ldz(const float* __restrict__ img, int y, int x) {
    bool v = ((unsigned)y < (unsigned)HH) & ((unsigned)x < (unsigned)WW);
    int off = v ? (y * WW + x) : 0;
    float val = img[off];
    return v ? val : 0.0f;
}

// Axis mapping for zero-padded bilinear on a clamped 2x2 square:
// contribution along this axis == s * [(1-t)*I[c0] + t*I[c0+1]], c0 in [0, H-2].
__device__ __forceinline__ void axis_map(int y0, float wy, int H,
                                         int& c0, float& t, float& s) {
    if (y0 >= 0 && y0 <= H - 2)      { c0 = y0;    t = wy;   s = 1.0f; }
    else if (y0 == -1)               { c0 = 0;     t = 0.0f; s = wy; }
    else if (y0 == H - 1)            { c0 = H - 2; t = 1.0f; s = 1.0f - wy; }
    else                             { c0 = 0;     t = 0.0f; s = 0.0f; }
}

// ---------------------------------------------------------------------------
// Kernel 0: transpose weights [c=24][ci=8][k=9] -> wT[k=9][ci=8][c=24]
// (wT lives in bufA's storage — dead until prop iter 0 overwrites it)
// ---------------------------------------------------------------------------
__global__ void transpose_w_kernel(const float* __restrict__ w_oa, float* __restrict__ wT) {
    for (int i = threadIdx.x; i < 1728; i += 256) {
        const int k = i / 192;
        const int r = i - k * 192;
        const int ci = r / 24;
        const int c = r - ci * 24;
        wT[i] = w_oa[c * 72 + ci * 9 + k];
    }
}

// ---------------------------------------------------------------------------
// Kernel 1: per-pixel precompute (same math as round 3, new output layout).
// Per pixel: AFF4[2] (8 scale-folded softmax weights), BASE4[2] (8 clamped
// in-bounds base indices), T4[2] (8 packed f16 (ty,tx)), affC (center weight).
// Prop then needs NO bounds checks and reads 16B-wide streams.
// ---------------------------------------------------------------------------
__global__ __launch_bounds__(256) void precompute_kernel(
    const float* __restrict__ guidance,
    const float* __restrict__ confidence,
    const float* __restrict__ wT,
    const float* __restrict__ b_oa,
    const float* __restrict__ aff_scale,
    float4* __restrict__ AFF4,
    uint4* __restrict__ BASE4,
    uint4* __restrict__ T4,
    float* __restrict__ affC)
{
    const int p = blockIdx.x * 256 + threadIdx.x;
    const int b = p / HW;
    const int rem = p - b * HW;
    const int y = rem / WW;
    const int x = rem - y * WW;

    float acc[24];
    #pragma unroll
    for (int c = 0; c < 24; ++c) acc[c] = b_oa[c];   // uniform -> s_load

    const float* gb = guidance + (size_t)b * 8 * HW;

    #pragma unroll 1
    for (int kidx = 0; kidx < 9; ++kidx) {
        const int yy = y + kidx / 3 - 1;
        const int xx = x + kidx % 3 - 1;
        const bool valid = ((unsigned)yy < (unsigned)HH) & ((unsigned)xx < (unsigned)WW);
        const int base = valid ? (yy * WW + xx) : 0;
        float g[8];
        #pragma unroll
        for (int ci = 0; ci < 8; ++ci) {
            float v = gb[ci * HW + base];
            g[ci] = valid ? v : 0.0f;
        }
        const float* wk = wT + kidx * 192;   // uniform address -> scalar loads
        #pragma unroll
        for (int ci = 0; ci < 8; ++ci) {
            const float gv = g[ci];
            #pragma unroll
            for (int c = 0; c < 24; ++c)
                acc[c] = fmaf(gv, wk[ci * 24 + c], acc[c]);
        }
    }

    // --- affinity head ---
    const float inv_scale = 1.0f / (aff_scale[0] + 1e-8f);
    const float* cb = confidence + (size_t)b * HW;
    const float fy = (float)y, fx = (float)x;

    float affv[8];
    #pragma unroll
    for (int j = 0; j < 8; ++j) {
        const float oy = acc[j], ox = acc[8 + j];
        const float a = tanhf(acc[16 + j]) * inv_scale;
        const float ysj = fy + oy, xsj = fx + ox;   // conf sampled at p+off (no tap)
        const float y0f = floorf(ysj), x0f = floorf(xsj);
        const float wy = ysj - y0f, wx = xsj - x0f;
        const int y0 = (int)y0f, x0 = (int)x0f;
        const float v00 = ldz(cb, y0, x0),     v01 = ldz(cb, y0, x0 + 1);
        const float v10 = ldz(cb, y0 + 1, x0), v11 = ldz(cb, y0 + 1, x0 + 1);
        const float conf = v00 * (1.0f - wy) * (1.0f - wx) + v01 * (1.0f - wy) * wx
                         + v10 * wy * (1.0f - wx)          + v11 * wy * wx;
        affv[j] = a * conf;
    }

    float s = 1e-4f;
    #pragma unroll
    for (int j = 0; j < 8; ++j) s += fabsf(affv[j]);
    s = fmaxf(s, 1.0f);
    const float inv_s = 1.0f / s;
    float sum = 0.0f;
    #pragma unroll
    for (int j = 0; j < 8; ++j) { affv[j] *= inv_s; sum += affv[j]; }
    const float aref = 1.0f - sum;

    float m = aref;
    #pragma unroll
    for (int j = 0; j < 8; ++j) m = fmaxf(m, affv[j]);
    float e[8];
    float denom = 0.0f;
    #pragma unroll
    for (int j = 0; j < 8; ++j) { e[j] = expf(affv[j] - m); denom += e[j]; }
    denom += expf(aref - m);
    const float invden = 1.0f / denom;

    affC[p] = expf(aref - m) * invden;

    float aout[8];
    unsigned bout[8], tout[8];
    #pragma unroll
    for (int j = 0; j < 8; ++j) {
        const int t9 = (j < 4) ? j : j + 1;          // 9-tap index (skip center 4)
        const float khv = (float)(t9 / 3 - 1);
        const float kwv = (float)(t9 % 3 - 1);
        const float ys = (fy + khv) + acc[j];
        const float xs = (fx + kwv) + acc[8 + j];
        const float y0f = floorf(ys), x0f = floorf(xs);
        const float wy = ys - y0f, wx = xs - x0f;
        int y0c, x0c; float ty, tx, sy, sx;
        axis_map((int)y0f, wy, HH, y0c, ty, sy);
        axis_map((int)x0f, wx, WW, x0c, tx, sx);

        aout[j] = (e[j] * invden) * sy * sx;
        bout[j] = (unsigned)(y0c * WW + x0c);
        __half2 h2 = __floats2half2_rn(ty, tx);      // low = ty, high = tx
        tout[j] = __builtin_bit_cast(unsigned, h2);
    }
    AFF4[2 * p + 0] = make_float4(aout[0], aout[1], aout[2], aout[3]);
    AFF4[2 * p + 1] = make_float4(aout[4], aout[5], aout[6], aout[7]);
    BASE4[2 * p + 0] = make_uint4(bout[0], bout[1], bout[2], bout[3]);
    BASE4[2 * p + 1] = make_uint4(bout[4], bout[5], bout[6], bout[7]);
    T4[2 * p + 0] = make_uint4(tout[0], tout[1], tout[2], tout[3]);
    T4[2 * p + 1] = make_uint4(tout[4], tout[5], tout[6], tout[7]);
}

// ---------------------------------------------------------------------------
// Kernel 2: one propagation step. 18 launches, ping-pong buffers.
// Per wave: 6 x4 stream loads + affC + src + 16 dwordx2 gathers + 1 store.
// ---------------------------------------------------------------------------
__global__ __launch_bounds__(256) void prop_kernel(
    const float* __restrict__ src,
    float* __restrict__ dst,
    const float4* __restrict__ AFF4,
    const uint4* __restrict__ BASE4,
    const uint4* __restrict__ T4,
    const float* __restrict__ affC)
{
    const int p = blockIdx.x * 256 + threadIdx.x;
    const int b = p / HW;
    const float* fb = src + (size_t)b * HW;

    const float4 a0 = AFF4[2 * p + 0], a1 = AFF4[2 * p + 1];
    const uint4  b0 = BASE4[2 * p + 0], b1 = BASE4[2 * p + 1];
    const uint4  t0 = T4[2 * p + 0],  t1 = T4[2 * p + 1];

    float acc = affC[p] * src[p];   // center tap: exact sample at p

    auto tap = [&](float a, unsigned base, unsigned tw) {
        const float2 top2 = *reinterpret_cast<const float2*>(fb + base);
        const float2 bot2 = *reinterpret_cast<const float2*>(fb + base + WW);
        const float2 t = __half22float2(__builtin_bit_cast(__half2, tw)); // (ty, tx)
        const float top = fmaf(t.y, top2.y - top2.x, top2.x);
        const float bot = fmaf(t.y, bot2.y - bot2.x, bot2.x);
        acc = fmaf(a, fmaf(t.x, bot - top, top), acc);
    };
    tap(a0.x, b0.x, t0.x);
    tap(a0.y, b0.y, t0.y);
    tap(a0.z, b0.z, t0.z);
    tap(a0.w, b0.w, t0.w);
    tap(a1.x, b1.x, t1.x);
    tap(a1.y, b1.y, t1.y);
    tap(a1.z, b1.z, t1.z);
    tap(a1.w, b1.w, t1.w);

    dst[p] = acc;
}

extern "C" void kernel_launch(void* const* d_in, const int* in_sizes, int n_in,
                              void* d_out, int out_size, void* d_ws, size_t ws_size,
                              hipStream_t stream) {
    const float* feat_init  = (const float*)d_in[0];
    const float* guidance   = (const float*)d_in[1];
    const float* confidence = (const float*)d_in[2];
    const float* w_oa       = (const float*)d_in[3];
    const float* b_oa       = (const float*)d_in[4];
    const float* aff_scale  = (const float*)d_in[5];
    float* out = (float*)d_out;
    float* ws  = (float*)d_ws;

    // ws layout (floats): AFF4[8P] | BASE4[8P] | T4[8P] | affC[P] | bufA[P]
    // wT (1728 floats) aliases bufA: dead once precompute has read it,
    // before prop iter 0 writes bufA (stream-ordered).
    const size_t need = (size_t)26 * PP * sizeof(float);
    if (ws_size < need) return;  // fail visibly rather than corrupt

    float4* AFF4  = reinterpret_cast<float4*>(ws);
    uint4*  BASE4 = reinterpret_cast<uint4*>(ws + (size_t)8 * PP);
    uint4*  T4    = reinterpret_cast<uint4*>(ws + (size_t)16 * PP);
    float*  affC  = ws + (size_t)24 * PP;
    float*  bufA  = ws + (size_t)25 * PP;
    float*  wT    = bufA;

    const int grid = PP / 256;
    transpose_w_kernel<<<1, 256, 0, stream>>>(w_oa, wT);
    precompute_kernel<<<grid, 256, 0, stream>>>(guidance, confidence, wT, b_oa,
                                                aff_scale, AFF4, BASE4, T4, affC);

    // ping-pong: even iters -> bufA, odd iters -> d_out (iter 17 -> d_out)
    const float* src = feat_init;
    for (int i = 0; i < 18; ++i) {
        float* dst = (i & 1) ? out : bufA;
        prop_kernel<<<grid, 256, 0, stream>>>(src, dst, AFF4, BASE4, T4, affC);
        src = dst;
    }
}

// Round 6
// 562.473 us; speedup vs baseline: 16.4984x; 1.0127x over previous
//
#include <hip/hip_runtime.h>
#include <hip/hip_fp16.h>
#include <math.h>

#define BB 4
#define HH 480
#define WW 640
#define HW (HH * WW)
#define PP (BB * HW)   // 1,228,800 pixels; PP % 256 == 0 (4800 blocks)

// Bilinear corner load with zero padding (precompute only)
__device__ __forceinline__ float ldz(const float* __restrict__ img, int y, int x) {
    bool v = ((unsigned)y < (unsigned)HH) & ((unsigned)x < (unsigned)WW);
    int off = v ? (y * WW + x) : 0;
    float val = img[off];
    return v ? val : 0.0f;
}

// Axis mapping for zero-padded bilinear on a clamped 2x2 square:
// contribution along this axis == s * [(1-t)*I[c0] + t*I[c0+1]], c0 in [0, H-2].
__device__ __forceinline__ void axis_map(int y0, float wy, int H,
                                         int& c0, float& t, float& s) {
    if (y0 >= 0 && y0 <= H - 2)      { c0 = y0;    t = wy;   s = 1.0f; }
    else if (y0 == -1)               { c0 = 0;     t = 0.0f; s = wy; }
    else if (y0 == H - 1)            { c0 = H - 2; t = 1.0f; s = 1.0f - wy; }
    else                             { c0 = 0;     t = 0.0f; s = 0.0f; }
}

// ---------------------------------------------------------------------------
// Kernel 0: transpose weights [c=24][ci=8][k=9] -> wT[k=9][ci=8][c=24]
// (wT lives in bufA's storage — dead until prop iter 0 overwrites it)
// ---------------------------------------------------------------------------
__global__ void transpose_w_kernel(const float* __restrict__ w_oa, float* __restrict__ wT) {
    for (int i = threadIdx.x; i < 1728; i += 256) {
        const int k = i / 192;
        const int r = i - k * 192;
        const int ci = r / 24;
        const int c = r - ci * 24;
        wT[i] = w_oa[c * 72 + ci * 9 + k];
    }
}

// ---------------------------------------------------------------------------
// Kernel 1: per-pixel precompute (same math; compressed output).
// Per tap j (8 B):  u32 { base19 (clamped in-bounds y0c*W+x0c) << 13 | aff13 }
//                   u32 { half2(ty, tx) }
// aff13 = round(softmax_aff * sy * sx * 8192)  (effective weight incl.
// zero-padding scale).  Center weight CANNOT be derived from the taps
// (out-of-bounds mass is lost, not redistributed) -> explicit affC stream,
// stored pre-scaled by 8192 to match the fixed-point taps.
// ---------------------------------------------------------------------------
__global__ __launch_bounds__(256) void precompute_kernel(
    const float* __restrict__ guidance,
    const float* __restrict__ confidence,
    const float* __restrict__ wT,
    const float* __restrict__ b_oa,
    const float* __restrict__ aff_scale,
    uint4* __restrict__ PK4,
    float* __restrict__ affC)
{
    const int p = blockIdx.x * 256 + threadIdx.x;
    const int b = p / HW;
    const int rem = p - b * HW;
    const int y = rem / WW;
    const int x = rem - y * WW;

    float acc[24];
    #pragma unroll
    for (int c = 0; c < 24; ++c) acc[c] = b_oa[c];   // uniform -> s_load

    const float* gb = guidance + (size_t)b * 8 * HW;

    #pragma unroll 1
    for (int kidx = 0; kidx < 9; ++kidx) {
        const int yy = y + kidx / 3 - 1;
        const int xx = x + kidx % 3 - 1;
        const bool valid = ((unsigned)yy < (unsigned)HH) & ((unsigned)xx < (unsigned)WW);
        const int base = valid ? (yy * WW + xx) : 0;
        float g[8];
        #pragma unroll
        for (int ci = 0; ci < 8; ++ci) {
            float v = gb[ci * HW + base];
            g[ci] = valid ? v : 0.0f;
        }
        const float* wk = wT + kidx * 192;   // uniform address -> scalar loads
        #pragma unroll
        for (int ci = 0; ci < 8; ++ci) {
            const float gv = g[ci];
            #pragma unroll
            for (int c = 0; c < 24; ++c)
                acc[c] = fmaf(gv, wk[ci * 24 + c], acc[c]);
        }
    }

    // --- affinity head ---
    const float inv_scale = 1.0f / (aff_scale[0] + 1e-8f);
    const float* cb = confidence + (size_t)b * HW;
    const float fy = (float)y, fx = (float)x;

    float affv[8];
    #pragma unroll
    for (int j = 0; j < 8; ++j) {
        const float oy = acc[j], ox = acc[8 + j];
        const float a = tanhf(acc[16 + j]) * inv_scale;
        const float ysj = fy + oy, xsj = fx + ox;   // conf sampled at p+off (no tap)
        const float y0f = floorf(ysj), x0f = floorf(xsj);
        const float wy = ysj - y0f, wx = xsj - x0f;
        const int y0 = (int)y0f, x0 = (int)x0f;
        const float v00 = ldz(cb, y0, x0),     v01 = ldz(cb, y0, x0 + 1);
        const float v10 = ldz(cb, y0 + 1, x0), v11 = ldz(cb, y0 + 1, x0 + 1);
        const float conf = v00 * (1.0f - wy) * (1.0f - wx) + v01 * (1.0f - wy) * wx
                         + v10 * wy * (1.0f - wx)          + v11 * wy * wx;
        affv[j] = a * conf;
    }

    float s = 1e-4f;
    #pragma unroll
    for (int j = 0; j < 8; ++j) s += fabsf(affv[j]);
    s = fmaxf(s, 1.0f);
    const float inv_s = 1.0f / s;
    float sum = 0.0f;
    #pragma unroll
    for (int j = 0; j < 8; ++j) { affv[j] *= inv_s; sum += affv[j]; }
    const float aref = 1.0f - sum;

    float m = aref;
    #pragma unroll
    for (int j = 0; j < 8; ++j) m = fmaxf(m, affv[j]);
    float e[8];
    float denom = 0.0f;
    #pragma unroll
    for (int j = 0; j < 8; ++j) { e[j] = expf(affv[j] - m); denom += e[j]; }
    denom += expf(aref - m);
    const float invden = 1.0f / denom;

    affC[p] = expf(aref - m) * invden * 8192.0f;   // pre-scaled center weight

    unsigned ba[8], tt[8];
    #pragma unroll
    for (int j = 0; j < 8; ++j) {
        const int t9 = (j < 4) ? j : j + 1;          // 9-tap index (skip center 4)
        const float khv = (float)(t9 / 3 - 1);
        const float kwv = (float)(t9 % 3 - 1);
        const float ys = (fy + khv) + acc[j];
        const float xs = (fx + kwv) + acc[8 + j];
        const float y0f = floorf(ys), x0f = floorf(xs);
        const float wy = ys - y0f, wx = xs - x0f;
        int y0c, x0c; float ty, tx, sy, sx;
        axis_map((int)y0f, wy, HH, y0c, ty, sy);
        axis_map((int)x0f, wx, WW, x0c, tx, sx);

        const float aeff = (e[j] * invden) * sy * sx;           // in [0,1)
        unsigned aq = __float2uint_rn(aeff * 8192.0f);
        aq = aq > 8191u ? 8191u : aq;
        ba[j] = ((unsigned)(y0c * WW + x0c) << 13) | aq;
        __half2 h2 = __floats2half2_rn(ty, tx);                 // low = ty, high = tx
        tt[j] = __builtin_bit_cast(unsigned, h2);
    }
    PK4[4 * p + 0] = make_uint4(ba[0], tt[0], ba[1], tt[1]);
    PK4[4 * p + 1] = make_uint4(ba[2], tt[2], ba[3], tt[3]);
    PK4[4 * p + 2] = make_uint4(ba[4], tt[4], ba[5], tt[5]);
    PK4[4 * p + 3] = make_uint4(ba[6], tt[6], ba[7], tt[7]);
}

// ---------------------------------------------------------------------------
// Kernel 2: one propagation step. 18 launches, ping-pong buffers.
// Streams per pixel: 64 B PK4 + 4 B affC + 4 B src + 4 B write.
// ---------------------------------------------------------------------------
__global__ __launch_bounds__(256) void prop_kernel(
    const float* __restrict__ src,
    float* __restrict__ dst,
    const uint4* __restrict__ PK4,
    const float* __restrict__ affC)
{
    const int p = blockIdx.x * 256 + threadIdx.x;
    const int b = p / HW;
    const float* fb = src + (size_t)b * HW;

    const uint4 q0 = PK4[4 * p + 0];
    const uint4 q1 = PK4[4 * p + 1];
    const uint4 q2 = PK4[4 * p + 2];
    const uint4 q3 = PK4[4 * p + 3];

    float acc = 0.0f;

    auto tap = [&](unsigned bav, unsigned tw) {
        const float af = (float)(bav & 8191u);
        const float* g = fb + (bav >> 13);
        const float2 top2 = *reinterpret_cast<const float2*>(g);
        const float2 bot2 = *reinterpret_cast<const float2*>(g + WW);
        const float2 t = __half22float2(__builtin_bit_cast(__half2, tw)); // (ty, tx)
        const float top = fmaf(t.y, top2.y - top2.x, top2.x);
        const float bot = fmaf(t.y, bot2.y - bot2.x, bot2.x);
        acc = fmaf(af, fmaf(t.x, bot - top, top), acc);
    };
    tap(q0.x, q0.y); tap(q0.z, q0.w);
    tap(q1.x, q1.y); tap(q1.z, q1.w);
    tap(q2.x, q2.y); tap(q2.z, q2.w);
    tap(q3.x, q3.y); tap(q3.z, q3.w);

    dst[p] = fmaf(affC[p], src[p], acc) * (1.0f / 8192.0f);
}

extern "C" void kernel_launch(void* const* d_in, const int* in_sizes, int n_in,
                              void* d_out, int out_size, void* d_ws, size_t ws_size,
                              hipStream_t stream) {
    const float* feat_init  = (const float*)d_in[0];
    const float* guidance   = (const float*)d_in[1];
    const float* confidence = (const float*)d_in[2];
    const float* w_oa       = (const float*)d_in[3];
    const float* b_oa       = (const float*)d_in[4];
    const float* aff_scale  = (const float*)d_in[5];
    float* out = (float*)d_out;
    float* ws  = (float*)d_ws;

    // ws layout (floats): PK4[16P] | affC[P] | bufA[P]
    // wT (1728 floats) aliases bufA: dead once precompute has read it,
    // before prop iter 0 writes bufA (stream-ordered).
    const size_t need = (size_t)18 * PP * sizeof(float);
    if (ws_size < need) return;  // fail visibly rather than corrupt

    uint4* PK4  = reinterpret_cast<uint4*>(ws);
    float* affC = ws + (size_t)16 * PP;
    float* bufA = ws + (size_t)17 * PP;
    float* wT   = bufA;

    const int grid = PP / 256;
    transpose_w_kernel<<<1, 256, 0, stream>>>(w_oa, wT);
    precompute_kernel<<<grid, 256, 0, stream>>>(guidance, confidence, wT, b_oa,
                                                aff_scale, PK4, affC);

    // ping-pong: even iters -> bufA, odd iters -> d_out (iter 17 -> d_out)
    const float* src = feat_init;
    for (int i = 0; i < 18; ++i) {
        float* dst = (i & 1) ? out : bufA;
        prop_kernel<<<grid, 256, 0, stream>>>(src, dst, PK4, affC);
        src = dst;
    }
}